// Round 10
// baseline (81.970 us; speedup 1.0000x reference)
//
#include <hip/hip_runtime.h>
#include <stdint.h>

// Problem constants (N=1, D=64, NCLS=21, R=C=512, R_IN=C_IN=256)
#define M_TOT 65536   // R_IN*C_IN
#define LBS_S 262144  // R*C
#define NBINS 1024    // 32x32 bins of 16x16 rp-sites
#define REC   24      // per-site record: n2(fp16) + 21 x lbs(u8) + 1 pad

typedef _Float16 h2 __attribute__((ext_vector_type(2)));
typedef float fx2 __attribute__((ext_vector_type(2)));

__device__ __forceinline__ int rfl(int v) { return __builtin_amdgcn_readfirstlane(v); }
__device__ __forceinline__ float bperm(int l, float v) {
  return __int_as_float(__builtin_amdgcn_ds_bpermute(l << 2, __float_as_int(v)));
}
__device__ __forceinline__ int bpermi(int l, int v) {
  return __builtin_amdgcn_ds_bpermute(l << 2, v);
}
// Multiplexed butterfly merge: lanes with `hi` keep reducing b, others a.
__device__ __forceinline__ float merge2(float a, float b, bool hi, int xo) {
  const float keep = hi ? b : a;
  const float send = hi ? a : b;
  return keep + __shfl_xor(send, xo, 64);
}

// ---------------- fp8 e4m3fn pack/unpack (HW path + SW fallback) ----------
#if __has_builtin(__builtin_amdgcn_cvt_pk_f32_fp8) && __has_builtin(__builtin_amdgcn_cvt_pk_fp8_f32)
#define FP8_HW 1
#endif

__device__ __forceinline__ uint32_t enc1_sw(float x) {
  uint32_t b = __float_as_uint(x);
  const uint32_t s = b >> 31;
  uint32_t ax = b & 0x7fffffffu;
  if (ax > 0x43e00000u) ax = 0x43e00000u;  // clamp to 448
  const int e = (int)(ax >> 23) - 127;
  uint32_t out;
  if (e >= -6) {
    const uint32_t r = ax + 0x00080000u;  // round-half-up at 3-bit mantissa
    const int e2 = (int)(r >> 23) - 127;
    if (e2 > 8) out = (15u << 3) | 6u;    // 448
    else out = ((uint32_t)(e2 + 7) << 3) | ((r >> 20) & 7u);
  } else if (e >= -10) {
    const float af = __uint_as_float(ax);
    int m = (int)(af * 512.0f + 0.5f);    // subnormal step 2^-9
    out = (m > 7) ? ((1u << 3) | 0u) : (uint32_t)m;
  } else {
    out = 0;
  }
  return out | (s << 7);
}
__device__ __forceinline__ float dec1_sw(uint32_t b) {
  const uint32_t e = (b >> 3) & 15u, m = b & 7u;
  float f;
  if (e) f = __uint_as_float(((e + 120u) << 23) | (m << 20));
  else f = (float)m * 0.001953125f;  // m * 2^-9
  return (b & 0x80u) ? -f : f;
}

__device__ __forceinline__ uint32_t enc_pk4(float a, float b, float c, float d) {
#ifdef FP8_HW
  int r = __builtin_amdgcn_cvt_pk_fp8_f32(a, b, 0, false);
  r = __builtin_amdgcn_cvt_pk_fp8_f32(c, d, r, true);
  return (uint32_t)r;
#else
  return enc1_sw(a) | (enc1_sw(b) << 8) | (enc1_sw(c) << 16) | (enc1_sw(d) << 24);
#endif
}
__device__ __forceinline__ void dec_pk8(uint32_t lo, uint32_t hi, float* o) {
#ifdef FP8_HW
  const fx2 a = __builtin_amdgcn_cvt_pk_f32_fp8((int)lo, false);
  const fx2 b = __builtin_amdgcn_cvt_pk_f32_fp8((int)lo, true);
  const fx2 c = __builtin_amdgcn_cvt_pk_f32_fp8((int)hi, false);
  const fx2 d = __builtin_amdgcn_cvt_pk_f32_fp8((int)hi, true);
  o[0] = a.x; o[1] = a.y; o[2] = b.x; o[3] = b.y;
  o[4] = c.x; o[5] = c.y; o[6] = d.x; o[7] = d.y;
#else
  o[0] = dec1_sw(lo & 255); o[1] = dec1_sw((lo >> 8) & 255);
  o[2] = dec1_sw((lo >> 16) & 255); o[3] = dec1_sw(lo >> 24);
  o[4] = dec1_sw(hi & 255); o[5] = dec1_sw((hi >> 8) & 255);
  o[6] = dec1_sw((hi >> 16) & 255); o[7] = dec1_sw(hi >> 24);
#endif
}

__device__ __forceinline__ int pixel_key(const float* grid_inte, const float* grid, int i) {
  const float dx = grid[(2 * 512 + 2) * 2 + 0] - grid[(1 * 512 + 2) * 2 + 0];
  const float dy = grid[(2 * 512 + 2) * 2 + 1] - grid[(2 * 512 + 1) * 2 + 1];
  const int rp0 = (int)floorf(grid_inte[i * 2 + 0] / dx);
  const int rp1 = (int)floorf(grid_inte[i * 2 + 1] / dy);
  return ((rp0 >> 4) << 5) | (rp1 >> 4);  // 32x32 bins
}

// ---------------------------------------------------------------------------
// Fused prep: blocks 0-1023: feat (64,65536)f32 -> feat_q (65536,64)fp8.
// Blocks 1024-2047: lbs (21,262144)f32 -> u8 into the 24B/site record
// (bytes 2..22; n2 slot filled by k_n2). Block 0 zeroes the histogram
// (counted by k_n2, which runs after — stream-ordered, no race).
// ---------------------------------------------------------------------------
__global__ __launch_bounds__(256) void k_prep(const float* __restrict__ feat,
                                              const float* __restrict__ lbs,
                                              uint8_t* __restrict__ feat_q,
                                              uint8_t* __restrict__ rec,
                                              int* __restrict__ hist) {
  __shared__ float ldsf[64 * 65];
  const int l = threadIdx.x & 63;
  const int w = threadIdx.x >> 6;
  if (blockIdx.x == 0) {
#pragma unroll
    for (int k = 0; k < 4; ++k) hist[k * 256 + threadIdx.x] = 0;
  }
  if (blockIdx.x < 1024) {
    float(*tile)[65] = (float(*)[65])ldsf;
    const int s0 = blockIdx.x * 64;
#pragma unroll
    for (int k = 0; k < 16; ++k) {
      const int d = w * 16 + k;
      tile[d][l] = feat[(size_t)d * M_TOT + s0 + l];
    }
    __syncthreads();
    // fp8 table: lane = (site-sub l>>3, chan-block cb = l&7)
    uint2* outq = (uint2*)feat_q;
#pragma unroll
    for (int it = 0; it < 2; ++it) {
      const int s = w * 16 + it * 8 + (l >> 3);
      const int cb = l & 7;
      const float* col = &tile[8 * cb][s];
      uint2 u;
      u.x = enc_pk4(col[0 * 65], col[1 * 65], col[2 * 65], col[3 * 65]);
      u.y = enc_pk4(col[4 * 65], col[5 * 65], col[6 * 65], col[7 * 65]);
      outq[(size_t)(s0 + s) * 8 + cb] = u;  // 512B coalesced
    }
  } else {
    uint8_t* buf = ((uint8_t*)ldsf) + w * (64 * REC);
    const int sb = (blockIdx.x - 1024) * 256 + w * 64;
#pragma unroll
    for (int c = 0; c < 21; ++c)
      buf[l * REC + 2 + c] = (uint8_t)(lbs[(size_t)c * LBS_S + sb + l] * 255.0f + 0.5f);
    __syncthreads();
    const uint32_t* src = (const uint32_t*)buf;
    uint32_t* dst = (uint32_t*)(rec + (size_t)sb * REC);  // 64*24=1536B, aligned
#pragma unroll
    for (int k = 0; k < 6; ++k) dst[k * 64 + l] = src[k * 64 + l];  // 384 dwords
  }
}

// ---------------------------------------------------------------------------
// N2[site] = ||feat_grid[:, site]||^2 from the FP8 table, written as fp16 into
// rec[site].n2. 8 quads per wave. Blocks 0-255 also histogram the pixels.
// ---------------------------------------------------------------------------
__global__ __launch_bounds__(256) void k_n2(const uint8_t* __restrict__ feat_q,
                                            uint8_t* __restrict__ rec,
                                            const float* __restrict__ grid_inte,
                                            const float* __restrict__ grid,
                                            int* __restrict__ hist) {
  if (blockIdx.x < 256) {
    const int i = blockIdx.x * 256 + threadIdx.x;
    atomicAdd(&hist[pixel_key(grid_inte, grid, i)], 1);
  }
  const int lane = threadIdx.x & 63;
  const int cb = lane & 7;
  const int g = lane >> 3;
  const int quad = blockIdx.x * 32 + (int)(threadIdx.x >> 6) * 8 + g;
  const int a = quad >> 8;
  const int b = quad & 255;
  const int ra[3] = {max(a - 1, 0), a, min(a + 1, 255)};
  const int cbn[3] = {max(b - 1, 0), b, min(b + 1, 255)};

  const uint2* fq = (const uint2*)feat_q;
  float F[3][3][8];
#pragma unroll
  for (int i = 0; i < 3; ++i)
#pragma unroll
    for (int j = 0; j < 3; ++j) {
      const uint2 u = fq[(size_t)((ra[i] << 8) + cbn[j]) * 8 + cb];
      dec_pk8(u.x, u.y, F[i][j]);
    }

  float wye[2], wxe[2];
  int cye[2], cxe[2];
#pragma unroll
  for (int e = 0; e < 2; ++e) {
    const float yf = fminf(fmaxf((float)(2 * a + e) * 0.5f - 0.25f, 0.0f), 255.0f);
    const int y0 = min((int)yf, 254);
    wye[e] = yf - (float)y0;
    cye[e] = y0 - (a - 1);
    const float xf = fminf(fmaxf((float)(2 * b + e) * 0.5f - 0.25f, 0.0f), 255.0f);
    const int x0 = min((int)xf, 254);
    wxe[e] = xf - (float)x0;
    cxe[e] = x0 - (b - 1);
  }

  float colv[3][2][8];
#pragma unroll
  for (int r = 0; r < 3; ++r)
#pragma unroll
    for (int e = 0; e < 2; ++e) {
      const bool s1 = (cxe[e] == 1);
#pragma unroll
      for (int j = 0; j < 8; ++j) {
        const float A = s1 ? F[r][1][j] : F[r][0][j];
        const float B = s1 ? F[r][2][j] : F[r][1][j];
        colv[r][e][j] = fmaf(wxe[e], B - A, A);
      }
    }

  float sq[4];
#pragma unroll
  for (int ey = 0; ey < 2; ++ey)
#pragma unroll
    for (int ex = 0; ex < 2; ++ex) {
      const bool s1 = (cye[ey] == 1);
      float nn = 0.0f;
#pragma unroll
      for (int j = 0; j < 8; ++j) {
        const float A = s1 ? colv[1][ex][j] : colv[0][ex][j];
        const float B = s1 ? colv[2][ex][j] : colv[1][ex][j];
        const float v = fmaf(wye[ey], B - A, A);
        nn = fmaf(v, v, nn);
      }
      sq[ey * 2 + ex] = nn;
    }

  const bool b0 = lane & 1, b1 = lane & 2;
  float m0 = merge2(sq[0], sq[1], b0, 1);
  float m1 = merge2(sq[2], sq[3], b0, 1);
  float mm = merge2(m0, m1, b1, 2);
  mm += __shfl_xor(mm, 4, 64);
  if ((lane & 7) < 4) {
    const int ey = (lane >> 1) & 1, ex = lane & 1;
    *(_Float16*)(rec + (size_t)((2 * a + ey) * 512 + 2 * b + ex) * REC) = (_Float16)mm;
  }
}

// Exclusive scan of 1024 bins -> cursor (single block, 256 threads).
__global__ __launch_bounds__(256) void k_scan(const int* __restrict__ hist,
                                              int* __restrict__ cursor) {
  __shared__ int wsum[4];
  const int t = threadIdx.x;
  const int4 h = ((const int4*)hist)[t];
  const int s = h.x + h.y + h.z + h.w;
  int sc = s;
#pragma unroll
  for (int o = 1; o < 64; o <<= 1) {
    const int u = __shfl_up(sc, o, 64);
    if ((t & 63) >= o) sc += u;
  }
  if ((t & 63) == 63) wsum[t >> 6] = sc;
  __syncthreads();
  int base = 0;
  for (int wv = 0; wv < (t >> 6); ++wv) base += wsum[wv];
  const int ex = base + sc - s;
  cursor[4 * t + 0] = ex;
  cursor[4 * t + 1] = ex + h.x;
  cursor[4 * t + 2] = ex + h.x + h.y;
  cursor[4 * t + 3] = ex + h.x + h.y + h.z;
}

__global__ __launch_bounds__(256) void k_scatter(const float* __restrict__ grid_inte,
                                                 const float* __restrict__ grid,
                                                 int* __restrict__ cursor,
                                                 int* __restrict__ order) {
  const int i = blockIdx.x * 256 + threadIdx.x;
  const int pos = atomicAdd(&cursor[pixel_key(grid_inte, grid, i)], 1);
  order[pos] = i;
}

// ---------------------------------------------------------------------------
// Main kernel: TWO pixels per wave (px = lane>>5), pixels walked in bin-sorted
// order (NO block swizzle: consecutive bids = consecutive sorted positions, so
// temporally co-resident waves share a small hot window in every XCD's L2).
// Patch+center from the fp8 table; taps from the fused 24B record.
// ---------------------------------------------------------------------------
__global__ __launch_bounds__(256) void k_main(const float* __restrict__ grid_inte,
                                              const float* __restrict__ grid,
                                              const uint8_t* __restrict__ feat_q,
                                              const uint8_t* __restrict__ rec,
                                              const float* __restrict__ wei_p,
                                              const int* __restrict__ order,
                                              float* __restrict__ out) {
  const int lane = threadIdx.x & 63;
  const int P = lane >> 5;
  const int pos = (int)blockIdx.x * 8 + (int)(threadIdx.x >> 6) * 2 + P;
  const int m = order[pos];

  const float dx = grid[(2 * 512 + 2) * 2 + 0] - grid[(1 * 512 + 2) * 2 + 0];
  const float dy = grid[(2 * 512 + 2) * 2 + 1] - grid[(2 * 512 + 1) * 2 + 1];
  const float wei = wei_p[0];

  const float gi0 = grid_inte[m * 2 + 0];
  const float gi1 = grid_inte[m * 2 + 1];
  const int rp0 = (int)floorf(gi0 / dx);
  const int rp1 = (int)floorf(gi1 / dy);
  const int by = (rp0 - 3) >> 1;
  const int bx = (rp1 - 3) >> 1;

  const int cb = lane & 7;
  const int g2 = (lane >> 3) & 3;
  const uint2* fq = (const uint2*)feat_q;

  // ---- Issue loads: center + 4 patch rows (fp8, xx fixed per lane) ----
  const uint2 ck = fq[(size_t)m * 8 + cb];
  uint2 pk[4];
  const int xx = min(max(bx + g2, 0), 255);
#pragma unroll
  for (int k = 0; k < 4; ++k) {
    const int yy = min(max(by + k, 0), 255);
    pk[k] = fq[(size_t)((yy << 8) + xx) * 8 + cb];
  }

  // ---- Tap geometry (VALU only, overlaps loads) ----
  const int t = lane & 31;
  const int ti = (t * 13) >> 6;  // t/5
  const int tj = t - 5 * ti;
  const int r5 = min(max(rp0 + ti - 2, 0), 511);
  const int c5 = min(max(rp1 + tj - 2, 0), 511);
  const float yf = fminf(fmaxf((float)r5 * 0.5f - 0.25f, 0.0f), 255.0f);
  const int y0 = min((int)yf, 254);
  const float wy = yf - (float)y0;
  const int qy = y0 - by;  // in [0,2] for t<25
  const float xf = fminf(fmaxf((float)c5 * 0.5f - 0.25f, 0.0f), 255.0f);
  const int x0 = min((int)xf, 254);
  const float wx = xf - (float)x0;
  const int qx = x0 - bx;
  const int lidx = r5 * 512 + c5;

  // ---- n2 gather (fp16 in the fused record) ----
  const float n2g = (float)*(const _Float16*)(rec + (size_t)lidx * REC);

  // ---- Prefetch px0's 9 lbs vote gathers ----
  const int vg = (lane >= 42) ? 2 : ((lane >= 21) ? 1 : 0);
  const int cc = min(lane - 21 * vg, 20);
  float lg0[9];
#pragma unroll
  for (int it = 0; it < 9; ++it) {
    const int idxt = bpermi(3 * it + vg, lidx);
    lg0[it] = (float)rec[(size_t)idxt * REC + 2 + cc];
  }

  // ---- Dot stage: decode fp8 center + patch, f32 fma ----
  float cf[8];
  dec_pk8(ck.x, ck.y, cf);
  float nhp = 0.0f;
#pragma unroll
  for (int j = 0; j < 8; ++j) nhp = fmaf(cf[j], cf[j], nhp);
  nhp *= -0.5f;
  float pr[4];
#pragma unroll
  for (int k = 0; k < 4; ++k) {
    float pp[8];
    dec_pk8(pk[k].x, pk[k].y, pp);
    float acc = nhp;
#pragma unroll
    for (int j = 0; j < 8; ++j) acc = fmaf(pp[j], cf[j], acc);
    pr[k] = acc;
  }
  const bool hb0 = lane & 1, hb1 = lane & 2;
  float mm0 = merge2(pr[0], pr[1], hb0, 1);
  float mm1 = merge2(pr[2], pr[3], hb0, 1);
  float Dv = merge2(mm0, mm1, hb1, 2);
  Dv += __shfl_xor(Dv, 4, 64);
  // lane L holds D'_{P=L>>5, s=(L&3)*4+((L>>3)&3)}

  // ---- Bilinear in D' space ----
  const int pb = P << 5;
  const int s00 = qy * 4 + qx;
  const int s01 = s00 + 1, s10 = s00 + 4, s11 = s00 + 5;
  const int l00 = pb | ((s00 & 3) << 3) | (s00 >> 2);
  const int l01 = pb | ((s01 & 3) << 3) | (s01 >> 2);
  const int l10 = pb | ((s10 & 3) << 3) | (s10 >> 2);
  const int l11 = pb | ((s11 & 3) << 3) | (s11 >> 2);
  const float d00 = bperm(l00, Dv);
  const float d01 = bperm(l01, Dv);
  const float d10 = bperm(l10, Dv);
  const float d11 = bperm(l11, Dv);
  const float lo = fmaf(wx, d01 - d00, d00);
  const float hi = fmaf(wx, d11 - d10, d10);
  const float crossD = fmaf(wy, hi - lo, lo);

  const float mse = fmaf(-2.0f, crossD, n2g) * 0.015625f;  // /64
  float dist = __expf(-wei * mse);
  dist = (t < 25) ? dist : 0.0f;

  // ---- Issue px1's lbs gathers (hidden under px0's vote phase) ----
  float lg1[9];
#pragma unroll
  for (int it = 0; it < 9; ++it) {
    const int idxt = bpermi(32 + 3 * it + vg, lidx);
    lg1[it] = (float)rec[(size_t)idxt * REC + 2 + cc];
  }

  // ---- Vote phase A (px0), den folded ----
  float voteA = 0.0f, dsumA = 0.0f;
#pragma unroll
  for (int it = 0; it < 9; ++it) {
    const float dt = bperm(3 * it + vg, dist);
    voteA = fmaf(lg0[it], dt, voteA);
    dsumA += dt;
  }
  const float vA = voteA + bperm(lane + 21, voteA) + bperm(lane + 42, voteA);
  const float dA = dsumA + bperm(lane + 21, dsumA) + bperm(lane + 42, dsumA);

  // ---- Vote phase B (px1) ----
  float voteB = 0.0f, dsumB = 0.0f;
#pragma unroll
  for (int it = 0; it < 9; ++it) {
    const float dt = bperm(32 + 3 * it + vg, dist);
    voteB = fmaf(lg1[it], dt, voteB);
    dsumB += dt;
  }
  const float vB = voteB + bperm(lane + 21, voteB) + bperm(lane + 42, voteB);
  const float dB = dsumB + bperm(lane + 21, dsumB) + bperm(lane + 42, dsumB);

  const int mB = bpermi(lane + 32, m);  // px1's output index for lanes < 32
  const float s255 = 1.0f / 255.0f;     // u8 lbs dequant
  if (lane < 21) {
    out[lane * M_TOT + m]  = vA * s255 / fmaxf(dA, 1e-15f);
    out[lane * M_TOT + mB] = vB * s255 / fmaxf(dB, 1e-15f);
  }
}

extern "C" void kernel_launch(void* const* d_in, const int* in_sizes, int n_in,
                              void* d_out, int out_size, void* d_ws, size_t ws_size,
                              hipStream_t stream) {
  const float* grid_inte = (const float*)d_in[0];  // (1,256,256,2)
  const float* grid      = (const float*)d_in[1];  // (1,512,512,2)
  const float* feat      = (const float*)d_in[2];  // (1,64,256,256)
  const float* lbs       = (const float*)d_in[3];  // (1,21,512,512)
  const float* wei       = (const float*)d_in[4];  // scalar
  float* out = (float*)d_out;                      // (1,21,256,256)

  char* ws = (char*)d_ws;
  uint8_t* feat_q = (uint8_t*)ws;                   // 4,194,304 B
  uint8_t* rec    = (uint8_t*)(ws + 4194304);       // 6,291,456 B (262144 x 24)
  int*     order  = (int*)(ws + 10485760);          // 262,144 B
  int*     hist   = (int*)(ws + 10747904);          // 4,096 B
  int*     cursor = (int*)(ws + 10752000);          // 4,096 B

  hipLaunchKernelGGL(k_prep, dim3(2048), dim3(256), 0, stream, feat, lbs, feat_q, rec, hist);
  hipLaunchKernelGGL(k_n2, dim3(M_TOT / 32), dim3(256), 0, stream, feat_q, rec, grid_inte, grid, hist);
  hipLaunchKernelGGL(k_scan, dim3(1), dim3(256), 0, stream, hist, cursor);
  hipLaunchKernelGGL(k_scatter, dim3(M_TOT / 256), dim3(256), 0, stream, grid_inte, grid, cursor, order);
  hipLaunchKernelGGL(k_main, dim3(M_TOT / 8), dim3(256), 0, stream,
                     grid_inte, grid, feat_q, rec, wei, order, out);
}

// Round 11
// 48.489 us; speedup vs baseline: 1.6905x; 1.6905x over previous
//
#include <hip/hip_runtime.h>
#include <stdint.h>

// Problem constants (N=1, D=64, NCLS=21, R=C=512, R_IN=C_IN=256)
#define M_TOT 65536   // R_IN*C_IN
#define LBS_S 262144  // R*C
#define REC   24      // per-site record: n2(fp16) + 21 x lbs(u8) + 1 pad

typedef float fx2 __attribute__((ext_vector_type(2)));

__device__ __forceinline__ int rfl(int v) { return __builtin_amdgcn_readfirstlane(v); }
__device__ __forceinline__ float bperm(int l, float v) {
  return __int_as_float(__builtin_amdgcn_ds_bpermute(l << 2, __float_as_int(v)));
}
__device__ __forceinline__ int bpermi(int l, int v) {
  return __builtin_amdgcn_ds_bpermute(l << 2, v);
}
// Multiplexed butterfly merge: lanes with `hi` keep reducing b, others a.
__device__ __forceinline__ float merge2(float a, float b, bool hi, int xo) {
  const float keep = hi ? b : a;
  const float send = hi ? a : b;
  return keep + __shfl_xor(send, xo, 64);
}

// ---------------- fp8 e4m3fn pack/unpack (HW path + SW fallback) ----------
#if __has_builtin(__builtin_amdgcn_cvt_pk_f32_fp8) && __has_builtin(__builtin_amdgcn_cvt_pk_fp8_f32)
#define FP8_HW 1
#endif

__device__ __forceinline__ uint32_t enc1_sw(float x) {
  uint32_t b = __float_as_uint(x);
  const uint32_t s = b >> 31;
  uint32_t ax = b & 0x7fffffffu;
  if (ax > 0x43e00000u) ax = 0x43e00000u;  // clamp to 448
  const int e = (int)(ax >> 23) - 127;
  uint32_t out;
  if (e >= -6) {
    const uint32_t r = ax + 0x00080000u;  // round-half-up at 3-bit mantissa
    const int e2 = (int)(r >> 23) - 127;
    if (e2 > 8) out = (15u << 3) | 6u;    // 448
    else out = ((uint32_t)(e2 + 7) << 3) | ((r >> 20) & 7u);
  } else if (e >= -10) {
    const float af = __uint_as_float(ax);
    int m = (int)(af * 512.0f + 0.5f);    // subnormal step 2^-9
    out = (m > 7) ? ((1u << 3) | 0u) : (uint32_t)m;
  } else {
    out = 0;
  }
  return out | (s << 7);
}
__device__ __forceinline__ float dec1_sw(uint32_t b) {
  const uint32_t e = (b >> 3) & 15u, m = b & 7u;
  float f;
  if (e) f = __uint_as_float(((e + 120u) << 23) | (m << 20));
  else f = (float)m * 0.001953125f;  // m * 2^-9
  return (b & 0x80u) ? -f : f;
}

__device__ __forceinline__ uint32_t enc_pk4(float a, float b, float c, float d) {
#ifdef FP8_HW
  int r = __builtin_amdgcn_cvt_pk_fp8_f32(a, b, 0, false);
  r = __builtin_amdgcn_cvt_pk_fp8_f32(c, d, r, true);
  return (uint32_t)r;
#else
  return enc1_sw(a) | (enc1_sw(b) << 8) | (enc1_sw(c) << 16) | (enc1_sw(d) << 24);
#endif
}
__device__ __forceinline__ void dec_pk8(uint32_t lo, uint32_t hi, float* o) {
#ifdef FP8_HW
  const fx2 a = __builtin_amdgcn_cvt_pk_f32_fp8((int)lo, false);
  const fx2 b = __builtin_amdgcn_cvt_pk_f32_fp8((int)lo, true);
  const fx2 c = __builtin_amdgcn_cvt_pk_f32_fp8((int)hi, false);
  const fx2 d = __builtin_amdgcn_cvt_pk_f32_fp8((int)hi, true);
  o[0] = a.x; o[1] = a.y; o[2] = b.x; o[3] = b.y;
  o[4] = c.x; o[5] = c.y; o[6] = d.x; o[7] = d.y;
#else
  o[0] = dec1_sw(lo & 255); o[1] = dec1_sw((lo >> 8) & 255);
  o[2] = dec1_sw((lo >> 16) & 255); o[3] = dec1_sw(lo >> 24);
  o[4] = dec1_sw(hi & 255); o[5] = dec1_sw((hi >> 8) & 255);
  o[6] = dec1_sw((hi >> 16) & 255); o[7] = dec1_sw(hi >> 24);
#endif
}

// ---------------------------------------------------------------------------
// Fused prep: blocks 0-1023: feat (64,65536)f32 -> feat_q (65536,64)fp8.
// Blocks 1024-2047: lbs (21,262144)f32 -> u8 into the 24B/site record
// (bytes 2..22; n2 slot filled by k_n2).
// ---------------------------------------------------------------------------
__global__ __launch_bounds__(256) void k_prep(const float* __restrict__ feat,
                                              const float* __restrict__ lbs,
                                              uint8_t* __restrict__ feat_q,
                                              uint8_t* __restrict__ rec) {
  __shared__ float ldsf[64 * 65];
  const int l = threadIdx.x & 63;
  const int w = threadIdx.x >> 6;
  if (blockIdx.x < 1024) {
    float(*tile)[65] = (float(*)[65])ldsf;
    const int s0 = blockIdx.x * 64;
#pragma unroll
    for (int k = 0; k < 16; ++k) {
      const int d = w * 16 + k;
      tile[d][l] = feat[(size_t)d * M_TOT + s0 + l];
    }
    __syncthreads();
    // fp8 table: lane = (site-sub l>>3, chan-block cb = l&7)
    uint2* outq = (uint2*)feat_q;
#pragma unroll
    for (int it = 0; it < 2; ++it) {
      const int s = w * 16 + it * 8 + (l >> 3);
      const int cb = l & 7;
      const float* col = &tile[8 * cb][s];
      uint2 u;
      u.x = enc_pk4(col[0 * 65], col[1 * 65], col[2 * 65], col[3 * 65]);
      u.y = enc_pk4(col[4 * 65], col[5 * 65], col[6 * 65], col[7 * 65]);
      outq[(size_t)(s0 + s) * 8 + cb] = u;  // 512B coalesced
    }
  } else {
    uint8_t* buf = ((uint8_t*)ldsf) + w * (64 * REC);
    const int sb = (blockIdx.x - 1024) * 256 + w * 64;
#pragma unroll
    for (int c = 0; c < 21; ++c)
      buf[l * REC + 2 + c] = (uint8_t)(lbs[(size_t)c * LBS_S + sb + l] * 255.0f + 0.5f);
    __syncthreads();
    const uint32_t* src = (const uint32_t*)buf;
    uint32_t* dst = (uint32_t*)(rec + (size_t)sb * REC);  // 64*24=1536B, aligned
#pragma unroll
    for (int k = 0; k < 6; ++k) dst[k * 64 + l] = src[k * 64 + l];  // 384 dwords
  }
}

// ---------------------------------------------------------------------------
// N2[site] = ||feat_grid[:, site]||^2 from the FP8 table (consistent with the
// expansion in k_main), written as fp16 into rec[site].n2. 8 quads per wave.
// ---------------------------------------------------------------------------
__global__ __launch_bounds__(256) void k_n2(const uint8_t* __restrict__ feat_q,
                                            uint8_t* __restrict__ rec) {
  const int lane = threadIdx.x & 63;
  const int cb = lane & 7;
  const int g = lane >> 3;
  const int quad = blockIdx.x * 32 + (int)(threadIdx.x >> 6) * 8 + g;
  const int a = quad >> 8;
  const int b = quad & 255;
  const int ra[3] = {max(a - 1, 0), a, min(a + 1, 255)};
  const int cbn[3] = {max(b - 1, 0), b, min(b + 1, 255)};

  const uint2* fq = (const uint2*)feat_q;
  float F[3][3][8];
#pragma unroll
  for (int i = 0; i < 3; ++i)
#pragma unroll
    for (int j = 0; j < 3; ++j) {
      const uint2 u = fq[(size_t)((ra[i] << 8) + cbn[j]) * 8 + cb];
      dec_pk8(u.x, u.y, F[i][j]);
    }

  float wye[2], wxe[2];
  int cye[2], cxe[2];
#pragma unroll
  for (int e = 0; e < 2; ++e) {
    const float yf = fminf(fmaxf((float)(2 * a + e) * 0.5f - 0.25f, 0.0f), 255.0f);
    const int y0 = min((int)yf, 254);
    wye[e] = yf - (float)y0;
    cye[e] = y0 - (a - 1);
    const float xf = fminf(fmaxf((float)(2 * b + e) * 0.5f - 0.25f, 0.0f), 255.0f);
    const int x0 = min((int)xf, 254);
    wxe[e] = xf - (float)x0;
    cxe[e] = x0 - (b - 1);
  }

  float colv[3][2][8];
#pragma unroll
  for (int r = 0; r < 3; ++r)
#pragma unroll
    for (int e = 0; e < 2; ++e) {
      const bool s1 = (cxe[e] == 1);
#pragma unroll
      for (int j = 0; j < 8; ++j) {
        const float A = s1 ? F[r][1][j] : F[r][0][j];
        const float B = s1 ? F[r][2][j] : F[r][1][j];
        colv[r][e][j] = fmaf(wxe[e], B - A, A);
      }
    }

  float sq[4];
#pragma unroll
  for (int ey = 0; ey < 2; ++ey)
#pragma unroll
    for (int ex = 0; ex < 2; ++ex) {
      const bool s1 = (cye[ey] == 1);
      float nn = 0.0f;
#pragma unroll
      for (int j = 0; j < 8; ++j) {
        const float A = s1 ? colv[1][ex][j] : colv[0][ex][j];
        const float B = s1 ? colv[2][ex][j] : colv[1][ex][j];
        const float v = fmaf(wye[ey], B - A, A);
        nn = fmaf(v, v, nn);
      }
      sq[ey * 2 + ex] = nn;
    }

  const bool b0 = lane & 1, b1 = lane & 2;
  float m0 = merge2(sq[0], sq[1], b0, 1);
  float m1 = merge2(sq[2], sq[3], b0, 1);
  float mm = merge2(m0, m1, b1, 2);
  mm += __shfl_xor(mm, 4, 64);
  if ((lane & 7) < 4) {
    const int ey = (lane >> 1) & 1, ex = lane & 1;
    *(_Float16*)(rec + (size_t)((2 * a + ey) * 512 + 2 * b + ex) * REC) = (_Float16)mm;
  }
}

// ---------------------------------------------------------------------------
// Main kernel: TWO pixels per wave (px = lane>>5), contiguous m (coalesced
// center/grid_inte/output). Patch+center from the fp8 table (8B/lane loads);
// taps from the fused 24B record (n2 fp16 + 21 u8 lbs share cache lines).
// ---------------------------------------------------------------------------
__global__ __launch_bounds__(256) void k_main(const float* __restrict__ grid_inte,
                                              const float* __restrict__ grid,
                                              const uint8_t* __restrict__ feat_q,
                                              const uint8_t* __restrict__ rec,
                                              const float* __restrict__ wei_p,
                                              float* __restrict__ out) {
  const int lane = threadIdx.x & 63;
  const int P = lane >> 5;
  const int m0 = rfl((int)blockIdx.x * 8 + (int)(threadIdx.x >> 6) * 2);
  const int m = m0 + P;

  const float dx = grid[(2 * 512 + 2) * 2 + 0] - grid[(1 * 512 + 2) * 2 + 0];
  const float dy = grid[(2 * 512 + 2) * 2 + 1] - grid[(2 * 512 + 1) * 2 + 1];
  const float wei = wei_p[0];

  const float gi0 = grid_inte[m * 2 + 0];
  const float gi1 = grid_inte[m * 2 + 1];
  const int rp0 = (int)floorf(gi0 / dx);
  const int rp1 = (int)floorf(gi1 / dy);
  const int by = (rp0 - 3) >> 1;
  const int bx = (rp1 - 3) >> 1;

  const int cb = lane & 7;
  const int g2 = (lane >> 3) & 3;
  const uint2* fq = (const uint2*)feat_q;

  // ---- Issue loads: center + 4 patch rows (fp8, xx fixed per lane) ----
  const uint2 ck = fq[(size_t)m * 8 + cb];
  uint2 pk[4];
  const int xx = min(max(bx + g2, 0), 255);
#pragma unroll
  for (int k = 0; k < 4; ++k) {
    const int yy = min(max(by + k, 0), 255);
    pk[k] = fq[(size_t)((yy << 8) + xx) * 8 + cb];
  }

  // ---- Tap geometry (VALU only, overlaps loads) ----
  const int t = lane & 31;
  const int ti = (t * 13) >> 6;  // t/5
  const int tj = t - 5 * ti;
  const int r5 = min(max(rp0 + ti - 2, 0), 511);
  const int c5 = min(max(rp1 + tj - 2, 0), 511);
  const float yf = fminf(fmaxf((float)r5 * 0.5f - 0.25f, 0.0f), 255.0f);
  const int y0 = min((int)yf, 254);
  const float wy = yf - (float)y0;
  const int qy = y0 - by;  // in [0,2] for t<25
  const float xf = fminf(fmaxf((float)c5 * 0.5f - 0.25f, 0.0f), 255.0f);
  const int x0 = min((int)xf, 254);
  const float wx = xf - (float)x0;
  const int qx = x0 - bx;
  const int lidx = r5 * 512 + c5;

  // ---- n2 gather (fp16 in the fused record) ----
  const float n2g = (float)*(const _Float16*)(rec + (size_t)lidx * REC);

  // ---- Prefetch px0's 9 lbs vote gathers ----
  const int vg = (lane >= 42) ? 2 : ((lane >= 21) ? 1 : 0);
  const int cc = min(lane - 21 * vg, 20);
  float lg0[9];
#pragma unroll
  for (int it = 0; it < 9; ++it) {
    const int idxt = bpermi(3 * it + vg, lidx);
    lg0[it] = (float)rec[(size_t)idxt * REC + 2 + cc];
  }

  // ---- Dot stage: decode fp8 center + patch, f32 fma ----
  float cf[8];
  dec_pk8(ck.x, ck.y, cf);
  float nhp = 0.0f;
#pragma unroll
  for (int j = 0; j < 8; ++j) nhp = fmaf(cf[j], cf[j], nhp);
  nhp *= -0.5f;
  float pr[4];
#pragma unroll
  for (int k = 0; k < 4; ++k) {
    float pp[8];
    dec_pk8(pk[k].x, pk[k].y, pp);
    float acc = nhp;
#pragma unroll
    for (int j = 0; j < 8; ++j) acc = fmaf(pp[j], cf[j], acc);
    pr[k] = acc;
  }
  const bool hb0 = lane & 1, hb1 = lane & 2;
  float mm0 = merge2(pr[0], pr[1], hb0, 1);
  float mm1 = merge2(pr[2], pr[3], hb0, 1);
  float Dv = merge2(mm0, mm1, hb1, 2);
  Dv += __shfl_xor(Dv, 4, 64);
  // lane L holds D'_{P=L>>5, s=(L&3)*4+((L>>3)&3)}

  // ---- Bilinear in D' space ----
  const int pb = P << 5;
  const int s00 = qy * 4 + qx;
  const int s01 = s00 + 1, s10 = s00 + 4, s11 = s00 + 5;
  const int l00 = pb | ((s00 & 3) << 3) | (s00 >> 2);
  const int l01 = pb | ((s01 & 3) << 3) | (s01 >> 2);
  const int l10 = pb | ((s10 & 3) << 3) | (s10 >> 2);
  const int l11 = pb | ((s11 & 3) << 3) | (s11 >> 2);
  const float d00 = bperm(l00, Dv);
  const float d01 = bperm(l01, Dv);
  const float d10 = bperm(l10, Dv);
  const float d11 = bperm(l11, Dv);
  const float lo = fmaf(wx, d01 - d00, d00);
  const float hi = fmaf(wx, d11 - d10, d10);
  const float crossD = fmaf(wy, hi - lo, lo);

  const float mse = fmaf(-2.0f, crossD, n2g) * 0.015625f;  // /64
  float dist = __expf(-wei * mse);
  dist = (t < 25) ? dist : 0.0f;

  // ---- Issue px1's lbs gathers (hidden under px0's vote phase) ----
  float lg1[9];
#pragma unroll
  for (int it = 0; it < 9; ++it) {
    const int idxt = bpermi(32 + 3 * it + vg, lidx);
    lg1[it] = (float)rec[(size_t)idxt * REC + 2 + cc];
  }

  // ---- Vote phase A (px0), den folded ----
  float voteA = 0.0f, dsumA = 0.0f;
#pragma unroll
  for (int it = 0; it < 9; ++it) {
    const float dt = bperm(3 * it + vg, dist);
    voteA = fmaf(lg0[it], dt, voteA);
    dsumA += dt;
  }
  const float vA = voteA + bperm(lane + 21, voteA) + bperm(lane + 42, voteA);
  const float dA = dsumA + bperm(lane + 21, dsumA) + bperm(lane + 42, dsumA);

  // ---- Vote phase B (px1) ----
  float voteB = 0.0f, dsumB = 0.0f;
#pragma unroll
  for (int it = 0; it < 9; ++it) {
    const float dt = bperm(32 + 3 * it + vg, dist);
    voteB = fmaf(lg1[it], dt, voteB);
    dsumB += dt;
  }
  const float vB = voteB + bperm(lane + 21, voteB) + bperm(lane + 42, voteB);
  const float dB = dsumB + bperm(lane + 21, dsumB) + bperm(lane + 42, dsumB);

  const float s255 = 1.0f / 255.0f;  // u8 lbs dequant
  if (lane < 21) {
    out[lane * M_TOT + m0]     = vA * s255 / fmaxf(dA, 1e-15f);
    out[lane * M_TOT + m0 + 1] = vB * s255 / fmaxf(dB, 1e-15f);
  }
}

extern "C" void kernel_launch(void* const* d_in, const int* in_sizes, int n_in,
                              void* d_out, int out_size, void* d_ws, size_t ws_size,
                              hipStream_t stream) {
  const float* grid_inte = (const float*)d_in[0];  // (1,256,256,2)
  const float* grid      = (const float*)d_in[1];  // (1,512,512,2)
  const float* feat      = (const float*)d_in[2];  // (1,64,256,256)
  const float* lbs       = (const float*)d_in[3];  // (1,21,512,512)
  const float* wei       = (const float*)d_in[4];  // scalar
  float* out = (float*)d_out;                      // (1,21,256,256)

  char* ws = (char*)d_ws;
  uint8_t* feat_q = (uint8_t*)ws;                   // 4,194,304 B
  uint8_t* rec    = (uint8_t*)(ws + 4194304);       // 6,291,456 B (262144 x 24)

  hipLaunchKernelGGL(k_prep, dim3(2048), dim3(256), 0, stream, feat, lbs, feat_q, rec);
  hipLaunchKernelGGL(k_n2, dim3(M_TOT / 32), dim3(256), 0, stream, feat_q, rec);
  hipLaunchKernelGGL(k_main, dim3(M_TOT / 8), dim3(256), 0, stream,
                     grid_inte, grid, feat_q, rec, wei, out);
}

// Round 12
// 47.594 us; speedup vs baseline: 1.7223x; 1.0188x over previous
//
#include <hip/hip_runtime.h>
#include <stdint.h>

// Problem constants (N=1, D=64, NCLS=21, R=C=512, R_IN=C_IN=256)
#define M_TOT 65536   // R_IN*C_IN
#define LBS_S 262144  // R*C
#define REC   24      // per-site record: n2(fp16) + 21 x lbs(u8) + 1 pad

typedef float fx2 __attribute__((ext_vector_type(2)));

__device__ __forceinline__ int rfl(int v) { return __builtin_amdgcn_readfirstlane(v); }
__device__ __forceinline__ float bperm(int l, float v) {
  return __int_as_float(__builtin_amdgcn_ds_bpermute(l << 2, __float_as_int(v)));
}
__device__ __forceinline__ int bpermi(int l, int v) {
  return __builtin_amdgcn_ds_bpermute(l << 2, v);
}
// Multiplexed butterfly merge: lanes with `hi` keep reducing b, others a.
__device__ __forceinline__ float merge2(float a, float b, bool hi, int xo) {
  const float keep = hi ? b : a;
  const float send = hi ? a : b;
  return keep + __shfl_xor(send, xo, 64);
}

// ---------------- fp8 e4m3fn pack/unpack (HW path + SW fallback) ----------
#if __has_builtin(__builtin_amdgcn_cvt_pk_f32_fp8) && __has_builtin(__builtin_amdgcn_cvt_pk_fp8_f32)
#define FP8_HW 1
#endif

__device__ __forceinline__ uint32_t enc1_sw(float x) {
  uint32_t b = __float_as_uint(x);
  const uint32_t s = b >> 31;
  uint32_t ax = b & 0x7fffffffu;
  if (ax > 0x43e00000u) ax = 0x43e00000u;  // clamp to 448
  const int e = (int)(ax >> 23) - 127;
  uint32_t out;
  if (e >= -6) {
    const uint32_t r = ax + 0x00080000u;  // round-half-up at 3-bit mantissa
    const int e2 = (int)(r >> 23) - 127;
    if (e2 > 8) out = (15u << 3) | 6u;    // 448
    else out = ((uint32_t)(e2 + 7) << 3) | ((r >> 20) & 7u);
  } else if (e >= -10) {
    const float af = __uint_as_float(ax);
    int m = (int)(af * 512.0f + 0.5f);    // subnormal step 2^-9
    out = (m > 7) ? ((1u << 3) | 0u) : (uint32_t)m;
  } else {
    out = 0;
  }
  return out | (s << 7);
}
__device__ __forceinline__ float dec1_sw(uint32_t b) {
  const uint32_t e = (b >> 3) & 15u, m = b & 7u;
  float f;
  if (e) f = __uint_as_float(((e + 120u) << 23) | (m << 20));
  else f = (float)m * 0.001953125f;  // m * 2^-9
  return (b & 0x80u) ? -f : f;
}

__device__ __forceinline__ uint32_t enc_pk4(float a, float b, float c, float d) {
#ifdef FP8_HW
  int r = __builtin_amdgcn_cvt_pk_fp8_f32(a, b, 0, false);
  r = __builtin_amdgcn_cvt_pk_fp8_f32(c, d, r, true);
  return (uint32_t)r;
#else
  return enc1_sw(a) | (enc1_sw(b) << 8) | (enc1_sw(c) << 16) | (enc1_sw(d) << 24);
#endif
}
__device__ __forceinline__ void dec_pk8(uint32_t lo, uint32_t hi, float* o) {
#ifdef FP8_HW
  const fx2 a = __builtin_amdgcn_cvt_pk_f32_fp8((int)lo, false);
  const fx2 b = __builtin_amdgcn_cvt_pk_f32_fp8((int)lo, true);
  const fx2 c = __builtin_amdgcn_cvt_pk_f32_fp8((int)hi, false);
  const fx2 d = __builtin_amdgcn_cvt_pk_f32_fp8((int)hi, true);
  o[0] = a.x; o[1] = a.y; o[2] = b.x; o[3] = b.y;
  o[4] = c.x; o[5] = c.y; o[6] = d.x; o[7] = d.y;
#else
  o[0] = dec1_sw(lo & 255); o[1] = dec1_sw((lo >> 8) & 255);
  o[2] = dec1_sw((lo >> 16) & 255); o[3] = dec1_sw(lo >> 24);
  o[4] = dec1_sw(hi & 255); o[5] = dec1_sw((hi >> 8) & 255);
  o[6] = dec1_sw((hi >> 16) & 255); o[7] = dec1_sw(hi >> 24);
#endif
}
__device__ __forceinline__ void dec_pk16(uint4 u, float* o) {
  dec_pk8(u.x, u.y, o);
  dec_pk8(u.z, u.w, o + 8);
}

// ---------------------------------------------------------------------------
// Fused prep: blocks 0-1023: feat (64,65536)f32 -> feat_q (65536,64)fp8.
// Blocks 1024-2047: lbs (21,262144)f32 -> u8 into the 24B/site record
// (bytes 2..22; n2 slot filled by k_n2).
// ---------------------------------------------------------------------------
__global__ __launch_bounds__(256) void k_prep(const float* __restrict__ feat,
                                              const float* __restrict__ lbs,
                                              uint8_t* __restrict__ feat_q,
                                              uint8_t* __restrict__ rec) {
  __shared__ float ldsf[64 * 65];
  const int l = threadIdx.x & 63;
  const int w = threadIdx.x >> 6;
  if (blockIdx.x < 1024) {
    float(*tile)[65] = (float(*)[65])ldsf;
    const int s0 = blockIdx.x * 64;
#pragma unroll
    for (int k = 0; k < 16; ++k) {
      const int d = w * 16 + k;
      tile[d][l] = feat[(size_t)d * M_TOT + s0 + l];
    }
    __syncthreads();
    // fp8 table: lane = (site-sub l>>3, chan-block cb = l&7)
    uint2* outq = (uint2*)feat_q;
#pragma unroll
    for (int it = 0; it < 2; ++it) {
      const int s = w * 16 + it * 8 + (l >> 3);
      const int cb = l & 7;
      const float* col = &tile[8 * cb][s];
      uint2 u;
      u.x = enc_pk4(col[0 * 65], col[1 * 65], col[2 * 65], col[3 * 65]);
      u.y = enc_pk4(col[4 * 65], col[5 * 65], col[6 * 65], col[7 * 65]);
      outq[(size_t)(s0 + s) * 8 + cb] = u;  // 512B coalesced
    }
  } else {
    uint8_t* buf = ((uint8_t*)ldsf) + w * (64 * REC);
    const int sb = (blockIdx.x - 1024) * 256 + w * 64;
#pragma unroll
    for (int c = 0; c < 21; ++c)
      buf[l * REC + 2 + c] = (uint8_t)(lbs[(size_t)c * LBS_S + sb + l] * 255.0f + 0.5f);
    __syncthreads();
    const uint32_t* src = (const uint32_t*)buf;
    uint32_t* dst = (uint32_t*)(rec + (size_t)sb * REC);  // 64*24=1536B, aligned
#pragma unroll
    for (int k = 0; k < 6; ++k) dst[k * 64 + l] = src[k * 64 + l];  // 384 dwords
  }
}

// ---------------------------------------------------------------------------
// N2[site] = ||feat_grid[:, site]||^2 from the FP8 table (consistent with the
// expansion in k_main), written as fp16 into rec[site].n2. 8 quads per wave.
// ---------------------------------------------------------------------------
__global__ __launch_bounds__(256) void k_n2(const uint8_t* __restrict__ feat_q,
                                            uint8_t* __restrict__ rec) {
  const int lane = threadIdx.x & 63;
  const int cb = lane & 7;
  const int g = lane >> 3;
  const int quad = blockIdx.x * 32 + (int)(threadIdx.x >> 6) * 8 + g;
  const int a = quad >> 8;
  const int b = quad & 255;
  const int ra[3] = {max(a - 1, 0), a, min(a + 1, 255)};
  const int cbn[3] = {max(b - 1, 0), b, min(b + 1, 255)};

  const uint2* fq = (const uint2*)feat_q;
  float F[3][3][8];
#pragma unroll
  for (int i = 0; i < 3; ++i)
#pragma unroll
    for (int j = 0; j < 3; ++j) {
      const uint2 u = fq[(size_t)((ra[i] << 8) + cbn[j]) * 8 + cb];
      dec_pk8(u.x, u.y, F[i][j]);
    }

  float wye[2], wxe[2];
  int cye[2], cxe[2];
#pragma unroll
  for (int e = 0; e < 2; ++e) {
    const float yf = fminf(fmaxf((float)(2 * a + e) * 0.5f - 0.25f, 0.0f), 255.0f);
    const int y0 = min((int)yf, 254);
    wye[e] = yf - (float)y0;
    cye[e] = y0 - (a - 1);
    const float xf = fminf(fmaxf((float)(2 * b + e) * 0.5f - 0.25f, 0.0f), 255.0f);
    const int x0 = min((int)xf, 254);
    wxe[e] = xf - (float)x0;
    cxe[e] = x0 - (b - 1);
  }

  float colv[3][2][8];
#pragma unroll
  for (int r = 0; r < 3; ++r)
#pragma unroll
    for (int e = 0; e < 2; ++e) {
      const bool s1 = (cxe[e] == 1);
#pragma unroll
      for (int j = 0; j < 8; ++j) {
        const float A = s1 ? F[r][1][j] : F[r][0][j];
        const float B = s1 ? F[r][2][j] : F[r][1][j];
        colv[r][e][j] = fmaf(wxe[e], B - A, A);
      }
    }

  float sq[4];
#pragma unroll
  for (int ey = 0; ey < 2; ++ey)
#pragma unroll
    for (int ex = 0; ex < 2; ++ex) {
      const bool s1 = (cye[ey] == 1);
      float nn = 0.0f;
#pragma unroll
      for (int j = 0; j < 8; ++j) {
        const float A = s1 ? colv[1][ex][j] : colv[0][ex][j];
        const float B = s1 ? colv[2][ex][j] : colv[1][ex][j];
        const float v = fmaf(wye[ey], B - A, A);
        nn = fmaf(v, v, nn);
      }
      sq[ey * 2 + ex] = nn;
    }

  const bool b0 = lane & 1, b1 = lane & 2;
  float m0 = merge2(sq[0], sq[1], b0, 1);
  float m1 = merge2(sq[2], sq[3], b0, 1);
  float mm = merge2(m0, m1, b1, 2);
  mm += __shfl_xor(mm, 4, 64);
  if ((lane & 7) < 4) {
    const int ey = (lane >> 1) & 1, ex = lane & 1;
    *(_Float16*)(rec + (size_t)((2 * a + ey) * 512 + 2 * b + ex) * REC) = (_Float16)mm;
  }
}

// ---------------------------------------------------------------------------
// Main kernel: TWO pixels per wave (px = lane>>5), contiguous m.
// Dot stage: lane = (channel-quarter qb = L&3, site-group sg = (L>>2)&7);
// 16 fp8 channels per dwordx4 load; sites sg and 8+sg per lane (2 loads cover
// the 16-site patch). Reduce over qb via 1 multiplexed merge (site bit3 <-
// lane bit0) + xor(2). Lane L holds D'_{P, s=8*(L&1)+((L>>2)&7)};
// source lane for (P,s): (P<<5)|((s&7)<<2)|(s>>3).
// Both pixels' 18 lbs gathers are issued BEFORE the dot chain (latency).
// ---------------------------------------------------------------------------
__global__ __launch_bounds__(256) void k_main(const float* __restrict__ grid_inte,
                                              const float* __restrict__ grid,
                                              const uint8_t* __restrict__ feat_q,
                                              const uint8_t* __restrict__ rec,
                                              const float* __restrict__ wei_p,
                                              float* __restrict__ out) {
  const int lane = threadIdx.x & 63;
  const int P = lane >> 5;
  const int m0 = rfl((int)blockIdx.x * 8 + (int)(threadIdx.x >> 6) * 2);
  const int m = m0 + P;

  const float dx = grid[(2 * 512 + 2) * 2 + 0] - grid[(1 * 512 + 2) * 2 + 0];
  const float dy = grid[(2 * 512 + 2) * 2 + 1] - grid[(2 * 512 + 1) * 2 + 1];
  const float wei = wei_p[0];

  const float gi0 = grid_inte[m * 2 + 0];
  const float gi1 = grid_inte[m * 2 + 1];
  const int rp0 = (int)floorf(gi0 / dx);
  const int rp1 = (int)floorf(gi1 / dy);
  const int by = (rp0 - 3) >> 1;
  const int bx = (rp1 - 3) >> 1;

  const int qb = lane & 3;          // channel quarter (16 fp8)
  const int sg = (lane >> 2) & 7;   // site group
  const uint4* fq4 = (const uint4*)feat_q;

  // ---- Issue loads: center quarter + 2 patch sites (16B each) ----
  const uint4 ck = fq4[(size_t)m * 4 + qb];
  const int yyA = min(max(by + (sg >> 2), 0), 255);
  const int xxA = min(max(bx + (sg & 3), 0), 255);
  const uint4 pkA = fq4[(size_t)((yyA << 8) + xxA) * 4 + qb];
  const int yyB = min(max(by + 2 + (sg >> 2), 0), 255);  // sites 8+sg: rows 2,3
  const uint4 pkB = fq4[(size_t)((yyB << 8) + xxA) * 4 + qb];

  // ---- Tap geometry (VALU only, overlaps loads) ----
  const int t = lane & 31;
  const int ti = (t * 13) >> 6;  // t/5
  const int tj = t - 5 * ti;
  const int r5 = min(max(rp0 + ti - 2, 0), 511);
  const int c5 = min(max(rp1 + tj - 2, 0), 511);
  const float yf = fminf(fmaxf((float)r5 * 0.5f - 0.25f, 0.0f), 255.0f);
  const int y0 = min((int)yf, 254);
  const float wy = yf - (float)y0;
  const int qy = y0 - by;  // in [0,2] for t<25
  const float xf = fminf(fmaxf((float)c5 * 0.5f - 0.25f, 0.0f), 255.0f);
  const int x0 = min((int)xf, 254);
  const float wx = xf - (float)x0;
  const int qx = x0 - bx;
  const int lidx = r5 * 512 + c5;

  // ---- n2 gather (fp16 in the fused record) ----
  const float n2g = (float)*(const _Float16*)(rec + (size_t)lidx * REC);

  // ---- Prefetch BOTH pixels' lbs vote gathers (18 loads in flight) ----
  const int vg = (lane >= 42) ? 2 : ((lane >= 21) ? 1 : 0);
  const int cc = min(lane - 21 * vg, 20);
  float lg0[9], lg1[9];
#pragma unroll
  for (int it = 0; it < 9; ++it) {
    const int idxt = bpermi(3 * it + vg, lidx);
    lg0[it] = (float)rec[(size_t)idxt * REC + 2 + cc];
  }
#pragma unroll
  for (int it = 0; it < 9; ++it) {
    const int idxt = bpermi(32 + 3 * it + vg, lidx);
    lg1[it] = (float)rec[(size_t)idxt * REC + 2 + cc];
  }

  // ---- Dot stage: decode fp8, f32 fma; nhp partial folded per lane ----
  float cf[16];
  dec_pk16(ck, cf);
  float nhp = 0.0f;
#pragma unroll
  for (int j = 0; j < 16; ++j) nhp = fmaf(cf[j], cf[j], nhp);
  nhp *= -0.5f;
  float pA[16], pB[16];
  dec_pk16(pkA, pA);
  dec_pk16(pkB, pB);
  float prA = nhp, prB = nhp;
#pragma unroll
  for (int j = 0; j < 16; ++j) {
    prA = fmaf(pA[j], cf[j], prA);
    prB = fmaf(pB[j], cf[j], prB);
  }
  // Reduce over qb bits (0,1): bit0 multiplexes site-bit3, bit1 plain sum.
  float Dv = merge2(prA, prB, lane & 1, 1);
  Dv += __shfl_xor(Dv, 2, 64);
  // lane L holds D'_{P=L>>5, s=8*(L&1)+((L>>2)&7)}

  // ---- Bilinear in D' space ----
  const int pb = P << 5;
  const int s00 = qy * 4 + qx;
  const int s01 = s00 + 1, s10 = s00 + 4, s11 = s00 + 5;
  const int l00 = pb | ((s00 & 7) << 2) | (s00 >> 3);
  const int l01 = pb | ((s01 & 7) << 2) | (s01 >> 3);
  const int l10 = pb | ((s10 & 7) << 2) | (s10 >> 3);
  const int l11 = pb | ((s11 & 7) << 2) | (s11 >> 3);
  const float d00 = bperm(l00, Dv);
  const float d01 = bperm(l01, Dv);
  const float d10 = bperm(l10, Dv);
  const float d11 = bperm(l11, Dv);
  const float lo = fmaf(wx, d01 - d00, d00);
  const float hi = fmaf(wx, d11 - d10, d10);
  const float crossD = fmaf(wy, hi - lo, lo);

  const float mse = fmaf(-2.0f, crossD, n2g) * 0.015625f;  // /64
  float dist = __expf(-wei * mse);
  dist = (t < 25) ? dist : 0.0f;

  // ---- Vote phase A (px0), den folded ----
  float voteA = 0.0f, dsumA = 0.0f;
#pragma unroll
  for (int it = 0; it < 9; ++it) {
    const float dt = bperm(3 * it + vg, dist);
    voteA = fmaf(lg0[it], dt, voteA);
    dsumA += dt;
  }
  const float vA = voteA + bperm(lane + 21, voteA) + bperm(lane + 42, voteA);
  const float dA = dsumA + bperm(lane + 21, dsumA) + bperm(lane + 42, dsumA);

  // ---- Vote phase B (px1) ----
  float voteB = 0.0f, dsumB = 0.0f;
#pragma unroll
  for (int it = 0; it < 9; ++it) {
    const float dt = bperm(32 + 3 * it + vg, dist);
    voteB = fmaf(lg1[it], dt, voteB);
    dsumB += dt;
  }
  const float vB = voteB + bperm(lane + 21, voteB) + bperm(lane + 42, voteB);
  const float dB = dsumB + bperm(lane + 21, dsumB) + bperm(lane + 42, dsumB);

  const float s255 = 1.0f / 255.0f;  // u8 lbs dequant
  if (lane < 21) {
    out[lane * M_TOT + m0]     = vA * s255 / fmaxf(dA, 1e-15f);
    out[lane * M_TOT + m0 + 1] = vB * s255 / fmaxf(dB, 1e-15f);
  }
}

extern "C" void kernel_launch(void* const* d_in, const int* in_sizes, int n_in,
                              void* d_out, int out_size, void* d_ws, size_t ws_size,
                              hipStream_t stream) {
  const float* grid_inte = (const float*)d_in[0];  // (1,256,256,2)
  const float* grid      = (const float*)d_in[1];  // (1,512,512,2)
  const float* feat      = (const float*)d_in[2];  // (1,64,256,256)
  const float* lbs       = (const float*)d_in[3];  // (1,21,512,512)
  const float* wei       = (const float*)d_in[4];  // scalar
  float* out = (float*)d_out;                      // (1,21,256,256)

  char* ws = (char*)d_ws;
  uint8_t* feat_q = (uint8_t*)ws;                   // 4,194,304 B
  uint8_t* rec    = (uint8_t*)(ws + 4194304);       // 6,291,456 B (262144 x 24)

  hipLaunchKernelGGL(k_prep, dim3(2048), dim3(256), 0, stream, feat, lbs, feat_q, rec);
  hipLaunchKernelGGL(k_n2, dim3(M_TOT / 32), dim3(256), 0, stream, feat_q, rec);
  hipLaunchKernelGGL(k_main, dim3(M_TOT / 8), dim3(256), 0, stream,
                     grid_inte, grid, feat_q, rec, wei, out);
}